// Round 16
// baseline (233.147 us; speedup 1.0000x reference)
//
#include <hip/hip_runtime.h>
#include <hip/hip_bf16.h>

#define B_   64
#define L_   512
#define H2_  1024
#define M_   (B_ * L_)     // 32768
#define KSPLIT 16
#define KCH  (H2_ / KSPLIT)   // 64

typedef short bf16x8 __attribute__((ext_vector_type(8)));
typedef float f32x4  __attribute__((ext_vector_type(4)));
typedef ushort ushort8_t __attribute__((ext_vector_type(8)));

__device__ __forceinline__ ushort f2bf(float f) {
    uint x = __float_as_uint(f);
    uint r = (x + 0x7FFFu + ((x >> 16) & 1u)) >> 16;
    return (ushort)r;
}

__device__ __forceinline__ float fast_tanh(float x) {
    float ax = fabsf(x);
    float e  = __expf(-2.0f * ax);
    float t  = 1.0f - 2.0f * e / (1.0f + e);
    return copysignf(t, x);
}

__device__ __forceinline__ void gload_lds16(const ushort* g, ushort* l) {
    __builtin_amdgcn_global_load_lds(
        (const __attribute__((address_space(1))) void*)g,
        (__attribute__((address_space(3))) void*)l, 16, 0, 0);
}

// -------------------------------------------------------------------------
// convertA: pai_q fp32 -> bf16 row-major.
// -------------------------------------------------------------------------
__global__ __launch_bounds__(256) void convertA_kernel(
    const float* __restrict__ in, ushort* __restrict__ out)
{
    size_t i = ((size_t)blockIdx.x * 256 + threadIdx.x) * 8;
    float4 a = *(const float4*)&in[i];
    float4 b = *(const float4*)&in[i + 4];
    ushort8_t h;
    h[0] = f2bf(a.x); h[1] = f2bf(a.y); h[2] = f2bf(a.z); h[3] = f2bf(a.w);
    h[4] = f2bf(b.x); h[5] = f2bf(b.y); h[6] = f2bf(b.z); h[7] = f2bf(b.w);
    *(ushort8_t*)&out[i] = h;
}

// -------------------------------------------------------------------------
// dec split-K
// -------------------------------------------------------------------------
__global__ __launch_bounds__(256) void dec_split_kernel(
    const float* __restrict__ s_t_hat, const float* __restrict__ Wqs,
    float* __restrict__ dec_part)
{
    const int t  = threadIdx.x;
    const int n  = blockIdx.x * 64 + (t & 63);
    const int k0 = blockIdx.y * KCH;
    const int bg = t >> 6;

    float acc[16];
    #pragma unroll
    for (int i = 0; i < 16; ++i) acc[i] = 0.f;

    for (int k8 = 0; k8 < KCH; k8 += 8) {
        float w[8];
        #pragma unroll
        for (int kk = 0; kk < 8; ++kk)
            w[kk] = Wqs[(size_t)(k0 + k8 + kk) * H2_ + n];
        #pragma unroll
        for (int i = 0; i < 16; ++i) {
            const float* srow = &s_t_hat[(bg * 16 + i) * H2_ + k0 + k8];
            #pragma unroll
            for (int kk = 0; kk < 8; ++kk)
                acc[i] += srow[kk] * w[kk];
        }
    }
    #pragma unroll
    for (int i = 0; i < 16; ++i)
        dec_part[(size_t)blockIdx.y * (B_ * H2_) + (bg * 16 + i) * H2_ + n] = acc[i];
}

// -------------------------------------------------------------------------
// fused dec_reduce (blocks 0..255) + convertB transpose (blocks 256..1279)
// -------------------------------------------------------------------------
__global__ __launch_bounds__(256) void decred_convB_kernel(
    const float* __restrict__ dec_part, const float* __restrict__ bqs,
    float* __restrict__ dec,
    const float* __restrict__ W, ushort* __restrict__ outB)
{
    __shared__ float t[32][33];
    int bid = blockIdx.x;
    if (bid < 256) {
        int i = bid * 256 + threadIdx.x;   // 0..65535
        float s = bqs[i & (H2_ - 1)];
        #pragma unroll
        for (int p = 0; p < KSPLIT; ++p) s += dec_part[(size_t)p * (B_ * H2_) + i];
        dec[i] = s;
    } else {
        int cb = bid - 256;                // 0..1023
        int k0 = (cb & 31) * 32, n0 = (cb >> 5) * 32;
        int tx = threadIdx.x & 31, ty = threadIdx.x >> 5;
        #pragma unroll
        for (int r = 0; r < 4; ++r)
            t[ty + r * 8][tx] = W[(size_t)(k0 + ty + r * 8) * H2_ + n0 + tx];
        __syncthreads();
        #pragma unroll
        for (int r = 0; r < 4; ++r)
            outB[(size_t)(n0 + ty + r * 8) * H2_ + k0 + tx] = f2bf(t[tx][ty + r * 8]);
    }
}

// -------------------------------------------------------------------------
// Fallback dec (monolithic) — only if ws too small.
// -------------------------------------------------------------------------
__global__ __launch_bounds__(256) void dec_kernel(
    const float* __restrict__ s_t_hat, const float* __restrict__ Wqs,
    const float* __restrict__ bqs, float* __restrict__ dec)
{
    int n  = blockIdx.x * 256 + threadIdx.x;
    int b0 = blockIdx.y * 4;
    float a0 = 0.f, a1 = 0.f, a2 = 0.f, a3 = 0.f;
    for (int h = 0; h < H2_; ++h) {
        float w = Wqs[h * H2_ + n];
        a0 += s_t_hat[(b0 + 0) * H2_ + h] * w;
        a1 += s_t_hat[(b0 + 1) * H2_ + h] * w;
        a2 += s_t_hat[(b0 + 2) * H2_ + h] * w;
        a3 += s_t_hat[(b0 + 3) * H2_ + h] * w;
    }
    float bias = bqs[n];
    dec[(b0 + 0) * H2_ + n] = a0 + bias;
    dec[(b0 + 1) * H2_ + n] = a1 + bias;
    dec[(b0 + 2) * H2_ + n] = a2 + bias;
    dec[(b0 + 3) * H2_ + n] = a3 + bias;
}

// -------------------------------------------------------------------------
// score v7: v3 structure with BN=256 (waves 2m x 2n, wave = 64 rows x 128
// cols, acc[4][8]). LDS reads/FLOP -25%, barriers/FLOP -50%, A L2 re-reads
// 8->4. Same XOR swizzle (involution on 8-chunk rows), same staging.
// scores_part now 8 groups: (blockIdx.y*2 + wn), blockIdx.y 0..3.
// -------------------------------------------------------------------------
#define BM 128
#define BN7 256
#define BK 64

__global__ __launch_bounds__(256) void score_kernel7(
    const ushort* __restrict__ Abf,  // (M, 1024) bf16
    const ushort* __restrict__ Bbf,  // (1024 n, 1024 k) bf16
    const float* __restrict__ dec,
    const float* __restrict__ cov,
    const float* __restrict__ Wc,
    const float* __restrict__ vq,
    float* __restrict__ scores_part) // (8, M)
{
    __shared__ ushort As[BM * BK];    // 16 KB
    __shared__ ushort Bs[BN7 * BK];   // 32 KB

    const int tid  = threadIdx.x;
    const int lane = tid & 63;
    const int wave = tid >> 6;
    const int wm = wave >> 1, wn = wave & 1;
    const int m0 = blockIdx.x * BM;
    const int n0 = blockIdx.y * BN7;

    f32x4 acc[4][8] = {};

    const int srow = lane >> 3;               // 0..7
    const int scol = ((lane & 7) ^ srow) * 8; // swizzled ushort offset
    const size_t abase = (size_t)(m0 + wave * 32 + srow) * H2_ + scol;
    const size_t bbase = (size_t)(n0 + wave * 64 + srow) * H2_ + scol;
    ushort* lA = As + wave * 32 * BK;
    ushort* lB = Bs + wave * 64 * BK;

    const int fr = lane & 15;
    const int fg = lane >> 4;
    const int fx = fr & 7;

    for (int kt = 0; kt < H2_; kt += BK) {
        #pragma unroll
        for (int p = 0; p < 4; ++p)
            gload_lds16(Abf + abase + (size_t)p * 8 * H2_ + kt, lA + p * 8 * BK);
        #pragma unroll
        for (int p = 0; p < 8; ++p)
            gload_lds16(Bbf + bbase + (size_t)p * 8 * H2_ + kt, lB + p * 8 * BK);
        __syncthreads();

        bf16x8 af[4][2];
        #pragma unroll
        for (int i = 0; i < 4; ++i)
            #pragma unroll
            for (int ks = 0; ks < 2; ++ks)
                af[i][ks] = *(const bf16x8*)
                    &As[(wm * 64 + i * 16 + fr) * BK + (((fg + ks * 4) ^ fx) * 8)];

        #pragma unroll
        for (int j = 0; j < 8; ++j) {
            bf16x8 b0 = *(const bf16x8*)
                &Bs[(wn * 128 + j * 16 + fr) * BK + ((fg ^ fx) * 8)];
            bf16x8 b1 = *(const bf16x8*)
                &Bs[(wn * 128 + j * 16 + fr) * BK + (((fg + 4) ^ fx) * 8)];
            #pragma unroll
            for (int i = 0; i < 4; ++i) {
                acc[i][j] = __builtin_amdgcn_mfma_f32_16x16x32_bf16(af[i][0], b0, acc[i][j], 0, 0, 0);
                acc[i][j] = __builtin_amdgcn_mfma_f32_16x16x32_bf16(af[i][1], b1, acc[i][j], 0, 0, 0);
            }
        }
        __syncthreads();
    }

    const int b = m0 >> 9;
    float dec8[8], wc8[8], vq8[8];
    #pragma unroll
    for (int j = 0; j < 8; ++j) {
        int n = n0 + wn * 128 + j * 16 + fr;
        dec8[j] = dec[b * H2_ + n];
        wc8[j]  = Wc[n];
        vq8[j]  = vq[n];
    }
    #pragma unroll
    for (int i = 0; i < 4; ++i) {
        #pragma unroll
        for (int r = 0; r < 4; ++r) {
            int ml = wm * 64 + i * 16 + fg * 4 + r;
            int m  = m0 + ml;
            float cv = cov[b * L_ + (m & (L_ - 1))];
            float s = 0.f;
            #pragma unroll
            for (int j = 0; j < 8; ++j) {
                float att = acc[i][j][r] + dec8[j] + cv * wc8[j];
                s += fast_tanh(att) * vq8[j];
            }
            s += __shfl_xor(s, 1);
            s += __shfl_xor(s, 2);
            s += __shfl_xor(s, 4);
            s += __shfl_xor(s, 8);
            if (fr == 0)
                scores_part[(size_t)(blockIdx.y * 2 + wn) * M_ + m] = s;
        }
    }
}

// -------------------------------------------------------------------------
// Fallback score (fp32 inputs, reg-staged) — only if ws too small.
// -------------------------------------------------------------------------
#define BN 128
#define LDK 40
__global__ __launch_bounds__(256) void score_kernel_fb(
    const float* __restrict__ A, const float* __restrict__ Bmat,
    const float* __restrict__ dec, const float* __restrict__ cov,
    const float* __restrict__ Wc, const float* __restrict__ vq,
    float* __restrict__ scores_part)
{
    __shared__ ushort As[BM * LDK];
    __shared__ ushort Bs[BN * LDK];
    const int tid  = threadIdx.x;
    const int lane = tid & 63;
    const int wave = tid >> 6;
    const int wm = wave >> 1, wn = wave & 1;
    const int m0 = blockIdx.x * BM;
    const int n0 = blockIdx.y * BN;
    f32x4 acc[4][4] = {};
    const int a_row = tid >> 3;
    const int a_kc  = (tid & 7) * 4;
    const int b_k  = tid >> 5;
    const int b_nc = (tid & 31) * 4;
    const int fr = lane & 15;
    const int fg = lane >> 4;
    for (int kt = 0; kt < H2_; kt += 32) {
        #pragma unroll
        for (int p = 0; p < 4; ++p) {
            int row = a_row + p * 32;
            float4 v = *(const float4*)&A[(size_t)(m0 + row) * H2_ + kt + a_kc];
            ushort4 h;
            h.x = f2bf(v.x); h.y = f2bf(v.y); h.z = f2bf(v.z); h.w = f2bf(v.w);
            *(ushort4*)&As[row * LDK + a_kc] = h;
        }
        #pragma unroll
        for (int p = 0; p < 4; ++p) {
            int k = b_k + p * 8;
            float4 v = *(const float4*)&Bmat[(size_t)(kt + k) * H2_ + n0 + b_nc];
            Bs[(b_nc + 0) * LDK + k] = f2bf(v.x);
            Bs[(b_nc + 1) * LDK + k] = f2bf(v.y);
            Bs[(b_nc + 2) * LDK + k] = f2bf(v.z);
            Bs[(b_nc + 3) * LDK + k] = f2bf(v.w);
        }
        __syncthreads();
        bf16x8 af[4], bfr[4];
        #pragma unroll
        for (int i = 0; i < 4; ++i)
            af[i] = *(const bf16x8*)&As[(wm * 64 + i * 16 + fr) * LDK + fg * 8];
        #pragma unroll
        for (int j = 0; j < 4; ++j)
            bfr[j] = *(const bf16x8*)&Bs[(wn * 64 + j * 16 + fr) * LDK + fg * 8];
        #pragma unroll
        for (int i = 0; i < 4; ++i)
            #pragma unroll
            for (int j = 0; j < 4; ++j)
                acc[i][j] = __builtin_amdgcn_mfma_f32_16x16x32_bf16(af[i], bfr[j], acc[i][j], 0, 0, 0);
        __syncthreads();
    }
    const int b = m0 >> 9;
    float dec4[4], wc4[4], vq4[4];
    #pragma unroll
    for (int j = 0; j < 4; ++j) {
        int n = n0 + wn * 64 + j * 16 + fr;
        dec4[j] = dec[b * H2_ + n];
        wc4[j]  = Wc[n];
        vq4[j]  = vq[n];
    }
    #pragma unroll
    for (int i = 0; i < 4; ++i) {
        #pragma unroll
        for (int r = 0; r < 4; ++r) {
            int ml = wm * 64 + i * 16 + fg * 4 + r;
            int m  = m0 + ml;
            float cv = cov[b * L_ + (m & (L_ - 1))];
            float s = 0.f;
            #pragma unroll
            for (int j = 0; j < 4; ++j) {
                float att = acc[i][j][r] + dec4[j] + cv * wc4[j];
                s += fast_tanh(att) * vq4[j];
            }
            s += __shfl_xor(s, 1);
            s += __shfl_xor(s, 2);
            s += __shfl_xor(s, 4);
            s += __shfl_xor(s, 8);
            if (fr == 0)
                scores_part[(size_t)(blockIdx.y * 2 + wn) * M_ + m] = s;
        }
    }
}

// -------------------------------------------------------------------------
// FUSED softmax + cqt (8 partial groups): grid (4 k-blocks, 64 b).
// -------------------------------------------------------------------------
__global__ __launch_bounds__(256) void softcqt_kernel(
    const float* __restrict__ scores_part, // (8, M)
    const float* __restrict__ mask,
    const float* __restrict__ cov,
    const ushort* __restrict__ Abf,        // (M, 1024) bf16
    float* __restrict__ out_alpha,
    float* __restrict__ out_newcov,
    float* __restrict__ c_q_t)
{
    const int b  = blockIdx.y;
    const int kb = blockIdx.x;       // 0..3
    const int t  = threadIdx.x;      // 0..255
    const int m0 = b * L_ + t;
    const int m1 = m0 + 256;

    float s0 = 0.f, s1 = 0.f;
    #pragma unroll
    for (int p = 0; p < 8; ++p) {
        s0 += scores_part[(size_t)p * M_ + m0];
        s1 += scores_part[(size_t)p * M_ + m1];
    }

    __shared__ float red[4];
    __shared__ float al[L_];

    float mx = fmaxf(s0, s1);
    #pragma unroll
    for (int o = 1; o < 64; o <<= 1) mx = fmaxf(mx, __shfl_xor(mx, o));
    if ((t & 63) == 0) red[t >> 6] = mx;
    __syncthreads();
    mx = fmaxf(fmaxf(red[0], red[1]), fmaxf(red[2], red[3]));
    __syncthreads();                  // red reuse guard

    float e0 = expf(s0 - mx) * mask[m0];
    float e1 = expf(s1 - mx) * mask[m1];
    float sm = e0 + e1;
    #pragma unroll
    for (int o = 1; o < 64; o <<= 1) sm += __shfl_xor(sm, o);
    if ((t & 63) == 0) red[t >> 6] = sm;
    __syncthreads();
    float tot = red[0] + red[1] + red[2] + red[3];

    float a0 = e0 / tot, a1 = e1 / tot;
    al[t]       = a0;
    al[t + 256] = a1;
    if (kb == 0) {
        out_alpha[m0]  = a0;
        out_alpha[m1]  = a1;
        out_newcov[m0] = cov[m0] + a0;
        out_newcov[m1] = cov[m1] + a1;
    }
    __syncthreads();

    const int k = kb * 256 + t;
    float acc = 0.f;
    const ushort* p = &Abf[(size_t)b * L_ * H2_ + k];
    #pragma unroll 8
    for (int l = 0; l < L_; ++l) {
        float v = __uint_as_float((uint)p[(size_t)l * H2_] << 16);
        acc += al[l] * v;
    }
    c_q_t[b * H2_ + k] = acc;
}

// -------------------------------------------------------------------------
// Fallback softmax / cqt (fp32, 16 groups) — only if ws too small.
// -------------------------------------------------------------------------
__global__ __launch_bounds__(512) void softmax_kernel(
    const float* __restrict__ scores_part,
    const float* __restrict__ mask,
    const float* __restrict__ cov,
    float* __restrict__ out_alpha,
    float* __restrict__ out_newcov)
{
    int b = blockIdx.x;
    int l = threadIdx.x;
    int m = b * L_ + l;
    float s = 0.f;
    #pragma unroll
    for (int p = 0; p < 16; ++p) s += scores_part[(size_t)p * M_ + m];
    __shared__ float red[8];
    float mx = s;
    #pragma unroll
    for (int o = 1; o < 64; o <<= 1) mx = fmaxf(mx, __shfl_xor(mx, o));
    int wid = l >> 6;
    if ((l & 63) == 0) red[wid] = mx;
    __syncthreads();
    mx = red[0];
    #pragma unroll
    for (int p = 1; p < 8; ++p) mx = fmaxf(mx, red[p]);
    __syncthreads();
    float e = expf(s - mx) * mask[m];
    float sm = e;
    #pragma unroll
    for (int o = 1; o < 64; o <<= 1) sm += __shfl_xor(sm, o);
    if ((l & 63) == 0) red[wid] = sm;
    __syncthreads();
    float tot = 0.f;
    #pragma unroll
    for (int p = 0; p < 8; ++p) tot += red[p];
    float alpha = e / tot;
    out_alpha[m]  = alpha;
    out_newcov[m] = cov[m] + alpha;
}

__global__ __launch_bounds__(256) void cqt_kernel(
    const float* __restrict__ alpha, const float* __restrict__ pai_q,
    float* __restrict__ out)
{
    int b = blockIdx.y;
    int k = blockIdx.x * 256 + threadIdx.x;
    __shared__ float al[L_];
    al[threadIdx.x]       = alpha[b * L_ + threadIdx.x];
    al[threadIdx.x + 256] = alpha[b * L_ + threadIdx.x + 256];
    __syncthreads();
    float acc = 0.f;
    const float* p = &pai_q[(size_t)b * L_ * H2_ + k];
    #pragma unroll 8
    for (int l = 0; l < L_; ++l) acc += al[l] * p[(size_t)l * H2_];
    out[b * H2_ + k] = acc;
}

extern "C" void kernel_launch(void* const* d_in, const int* in_sizes, int n_in,
                              void* d_out, int out_size, void* d_ws, size_t ws_size,
                              hipStream_t stream)
{
    const float* s_t_hat = (const float*)d_in[0];
    const float* pai_q   = (const float*)d_in[1];
    const float* mask    = (const float*)d_in[2];
    const float* cov     = (const float*)d_in[3];
    const float* W_q     = (const float*)d_in[4];
    const float* W_qs_w  = (const float*)d_in[5];
    const float* W_qs_b  = (const float*)d_in[6];
    const float* W_c     = (const float*)d_in[7];
    const float* v_q     = (const float*)d_in[8];

    float* out     = (float*)d_out;
    float* c_q_t   = out;
    float* alpha   = out + B_ * H2_;
    float* newcov  = alpha + B_ * L_;

    // ws: dec 262144 | scores_part 2097152 | Bbf 2097152 | Abf 67108864
    // dec_part (4 MB) time-aliases Abf (used before convertA writes it).
    char* ws = (char*)d_ws;
    float*  dec         = (float*)ws;
    float*  scores_part = (float*)(ws + 262144);
    ushort* Bbf         = (ushort*)(ws + 262144 + 2097152);
    ushort* Abf         = (ushort*)(ws + 262144 + 2097152 + 2097152);
    float*  dec_part    = (float*)Abf;
    const size_t ws_needed = 262144ull + 2097152ull + 2097152ull + 67108864ull;
    const size_t ws_min_fb = 262144ull + 2097152ull;

    if (ws_size >= ws_needed) {
        dec_split_kernel<<<dim3(16, KSPLIT), 256, 0, stream>>>(s_t_hat, W_qs_w, dec_part);
        decred_convB_kernel<<<dim3(1280), 256, 0, stream>>>(
            dec_part, W_qs_b, dec, W_q, Bbf);
        convertA_kernel<<<dim3((M_ * H2_) / (256 * 8)), 256, 0, stream>>>(pai_q, Abf);
        score_kernel7<<<dim3(M_ / BM, H2_ / BN7), 256, 0, stream>>>(
            Abf, Bbf, dec, cov, W_c, v_q, scores_part);
        softcqt_kernel<<<dim3(4, B_), 256, 0, stream>>>(
            scores_part, mask, cov, Abf, alpha, newcov, c_q_t);
    } else if (ws_size >= ws_min_fb) {
        dec_kernel<<<dim3(4, 16), 256, 0, stream>>>(s_t_hat, W_qs_w, W_qs_b, dec);
        score_kernel_fb<<<dim3(M_ / BM, H2_ / BN), 256, 0, stream>>>(
            pai_q, W_q, dec, cov, W_c, v_q, scores_part);
        softmax_kernel<<<dim3(B_), 512, 0, stream>>>(scores_part, mask, cov, alpha, newcov);
        cqt_kernel<<<dim3(4, B_), 256, 0, stream>>>(alpha, pai_q, c_q_t);
    }
}

// Round 17
// 183.448 us; speedup vs baseline: 1.2709x; 1.2709x over previous
//
#include <hip/hip_runtime.h>
#include <hip/hip_bf16.h>

#define B_   64
#define L_   512
#define H2_  1024
#define M_   (B_ * L_)     // 32768
#define KSPLIT 16
#define KCH  (H2_ / KSPLIT)   // 64

typedef short bf16x8 __attribute__((ext_vector_type(8)));
typedef float f32x4  __attribute__((ext_vector_type(4)));
typedef ushort ushort8_t __attribute__((ext_vector_type(8)));

__device__ __forceinline__ ushort f2bf(float f) {
    uint x = __float_as_uint(f);
    uint r = (x + 0x7FFFu + ((x >> 16) & 1u)) >> 16;
    return (ushort)r;
}

__device__ __forceinline__ float fast_tanh(float x) {
    float ax = fabsf(x);
    float e  = __expf(-2.0f * ax);
    float t  = 1.0f - 2.0f * e / (1.0f + e);
    return copysignf(t, x);
}

__device__ __forceinline__ void gload_lds16(const ushort* g, ushort* l) {
    __builtin_amdgcn_global_load_lds(
        (const __attribute__((address_space(1))) void*)g,
        (__attribute__((address_space(3))) void*)l, 16, 0, 0);
}

// -------------------------------------------------------------------------
// convertA: pai_q fp32 -> bf16 row-major.
// -------------------------------------------------------------------------
__global__ __launch_bounds__(256) void convertA_kernel(
    const float* __restrict__ in, ushort* __restrict__ out)
{
    size_t i = ((size_t)blockIdx.x * 256 + threadIdx.x) * 8;
    float4 a = *(const float4*)&in[i];
    float4 b = *(const float4*)&in[i + 4];
    ushort8_t h;
    h[0] = f2bf(a.x); h[1] = f2bf(a.y); h[2] = f2bf(a.z); h[3] = f2bf(a.w);
    h[4] = f2bf(b.x); h[5] = f2bf(b.y); h[6] = f2bf(b.z); h[7] = f2bf(b.w);
    *(ushort8_t*)&out[i] = h;
}

// -------------------------------------------------------------------------
// dec split-K
// -------------------------------------------------------------------------
__global__ __launch_bounds__(256) void dec_split_kernel(
    const float* __restrict__ s_t_hat, const float* __restrict__ Wqs,
    float* __restrict__ dec_part)
{
    const int t  = threadIdx.x;
    const int n  = blockIdx.x * 64 + (t & 63);
    const int k0 = blockIdx.y * KCH;
    const int bg = t >> 6;

    float acc[16];
    #pragma unroll
    for (int i = 0; i < 16; ++i) acc[i] = 0.f;

    for (int k8 = 0; k8 < KCH; k8 += 8) {
        float w[8];
        #pragma unroll
        for (int kk = 0; kk < 8; ++kk)
            w[kk] = Wqs[(size_t)(k0 + k8 + kk) * H2_ + n];
        #pragma unroll
        for (int i = 0; i < 16; ++i) {
            const float* srow = &s_t_hat[(bg * 16 + i) * H2_ + k0 + k8];
            #pragma unroll
            for (int kk = 0; kk < 8; ++kk)
                acc[i] += srow[kk] * w[kk];
        }
    }
    #pragma unroll
    for (int i = 0; i < 16; ++i)
        dec_part[(size_t)blockIdx.y * (B_ * H2_) + (bg * 16 + i) * H2_ + n] = acc[i];
}

// -------------------------------------------------------------------------
// fused dec_reduce (blocks 0..255) + convertB transpose (blocks 256..1279)
// -------------------------------------------------------------------------
__global__ __launch_bounds__(256) void decred_convB_kernel(
    const float* __restrict__ dec_part, const float* __restrict__ bqs,
    float* __restrict__ dec,
    const float* __restrict__ W, ushort* __restrict__ outB)
{
    __shared__ float t[32][33];
    int bid = blockIdx.x;
    if (bid < 256) {
        int i = bid * 256 + threadIdx.x;   // 0..65535
        float s = bqs[i & (H2_ - 1)];
        #pragma unroll
        for (int p = 0; p < KSPLIT; ++p) s += dec_part[(size_t)p * (B_ * H2_) + i];
        dec[i] = s;
    } else {
        int cb = bid - 256;                // 0..1023
        int k0 = (cb & 31) * 32, n0 = (cb >> 5) * 32;
        int tx = threadIdx.x & 31, ty = threadIdx.x >> 5;
        #pragma unroll
        for (int r = 0; r < 4; ++r)
            t[ty + r * 8][tx] = W[(size_t)(k0 + ty + r * 8) * H2_ + n0 + tx];
        __syncthreads();
        #pragma unroll
        for (int r = 0; r < 4; ++r)
            outB[(size_t)(n0 + ty + r * 8) * H2_ + k0 + tx] = f2bf(t[tx][ty + r * 8]);
    }
}

// -------------------------------------------------------------------------
// Fallback dec (monolithic) — only if ws too small.
// -------------------------------------------------------------------------
__global__ __launch_bounds__(256) void dec_kernel(
    const float* __restrict__ s_t_hat, const float* __restrict__ Wqs,
    const float* __restrict__ bqs, float* __restrict__ dec)
{
    int n  = blockIdx.x * 256 + threadIdx.x;
    int b0 = blockIdx.y * 4;
    float a0 = 0.f, a1 = 0.f, a2 = 0.f, a3 = 0.f;
    for (int h = 0; h < H2_; ++h) {
        float w = Wqs[h * H2_ + n];
        a0 += s_t_hat[(b0 + 0) * H2_ + h] * w;
        a1 += s_t_hat[(b0 + 1) * H2_ + h] * w;
        a2 += s_t_hat[(b0 + 2) * H2_ + h] * w;
        a3 += s_t_hat[(b0 + 3) * H2_ + h] * w;
    }
    float bias = bqs[n];
    dec[(b0 + 0) * H2_ + n] = a0 + bias;
    dec[(b0 + 1) * H2_ + n] = a1 + bias;
    dec[(b0 + 2) * H2_ + n] = a2 + bias;
    dec[(b0 + 3) * H2_ + n] = a3 + bias;
}

// -------------------------------------------------------------------------
// score v3 (measured-best): BK=64, XOR-swizzled LDS, fast tanh epilogue.
// -------------------------------------------------------------------------
#define BM 128
#define BN 128
#define BK 64

__global__ __launch_bounds__(256) void score_kernel3(
    const ushort* __restrict__ Abf,  // (M, 1024) bf16
    const ushort* __restrict__ Bbf,  // (1024 n, 1024 k) bf16
    const float* __restrict__ dec,
    const float* __restrict__ cov,
    const float* __restrict__ Wc,
    const float* __restrict__ vq,
    float* __restrict__ scores_part) // (16, M)
{
    __shared__ ushort As[BM * BK];
    __shared__ ushort Bs[BN * BK];

    const int tid  = threadIdx.x;
    const int lane = tid & 63;
    const int wave = tid >> 6;
    const int wm = wave >> 1, wn = wave & 1;
    const int m0 = blockIdx.x * BM;
    const int n0 = blockIdx.y * BN;

    f32x4 acc[4][4] = {};

    const int srow = lane >> 3;               // 0..7
    const int scol = ((lane & 7) ^ srow) * 8; // swizzled ushort offset
    const size_t abase = (size_t)(m0 + wave * 32 + srow) * H2_ + scol;
    const size_t bbase = (size_t)(n0 + wave * 32 + srow) * H2_ + scol;
    ushort* lA = As + wave * 32 * BK;
    ushort* lB = Bs + wave * 32 * BK;

    const int fr = lane & 15;
    const int fg = lane >> 4;
    const int fx = fr & 7;

    for (int kt = 0; kt < H2_; kt += BK) {
        #pragma unroll
        for (int p = 0; p < 4; ++p) {
            gload_lds16(Abf + abase + p * 8 * H2_ + kt, lA + p * 8 * BK);
            gload_lds16(Bbf + bbase + p * 8 * H2_ + kt, lB + p * 8 * BK);
        }
        __syncthreads();

        bf16x8 af[4][2];
        #pragma unroll
        for (int i = 0; i < 4; ++i)
            #pragma unroll
            for (int ks = 0; ks < 2; ++ks)
                af[i][ks] = *(const bf16x8*)
                    &As[(wm * 64 + i * 16 + fr) * BK + (((fg + ks * 4) ^ fx) * 8)];

        #pragma unroll
        for (int j = 0; j < 4; ++j) {
            bf16x8 b0 = *(const bf16x8*)
                &Bs[(wn * 64 + j * 16 + fr) * BK + ((fg ^ fx) * 8)];
            bf16x8 b1 = *(const bf16x8*)
                &Bs[(wn * 64 + j * 16 + fr) * BK + (((fg + 4) ^ fx) * 8)];
            #pragma unroll
            for (int i = 0; i < 4; ++i) {
                acc[i][j] = __builtin_amdgcn_mfma_f32_16x16x32_bf16(af[i][0], b0, acc[i][j], 0, 0, 0);
                acc[i][j] = __builtin_amdgcn_mfma_f32_16x16x32_bf16(af[i][1], b1, acc[i][j], 0, 0, 0);
            }
        }
        __syncthreads();
    }

    const int b = m0 >> 9;
    float dec4[4], wc4[4], vq4[4];
    #pragma unroll
    for (int j = 0; j < 4; ++j) {
        int n = n0 + wn * 64 + j * 16 + fr;
        dec4[j] = dec[b * H2_ + n];
        wc4[j]  = Wc[n];
        vq4[j]  = vq[n];
    }
    #pragma unroll
    for (int i = 0; i < 4; ++i) {
        #pragma unroll
        for (int r = 0; r < 4; ++r) {
            int ml = wm * 64 + i * 16 + fg * 4 + r;
            int m  = m0 + ml;
            float cv = cov[b * L_ + (m & (L_ - 1))];
            float s = 0.f;
            #pragma unroll
            for (int j = 0; j < 4; ++j) {
                float att = acc[i][j][r] + dec4[j] + cv * wc4[j];
                s += fast_tanh(att) * vq4[j];
            }
            s += __shfl_xor(s, 1);
            s += __shfl_xor(s, 2);
            s += __shfl_xor(s, 4);
            s += __shfl_xor(s, 8);
            if (fr == 0)
                scores_part[(size_t)(blockIdx.y * 2 + wn) * M_ + m] = s;
        }
    }
}

// -------------------------------------------------------------------------
// Fallback score (fp32 inputs, reg-staged) — only if ws too small.
// -------------------------------------------------------------------------
#define LDK 40
__global__ __launch_bounds__(256) void score_kernel_fb(
    const float* __restrict__ A, const float* __restrict__ Bmat,
    const float* __restrict__ dec, const float* __restrict__ cov,
    const float* __restrict__ Wc, const float* __restrict__ vq,
    float* __restrict__ scores_part)
{
    __shared__ ushort As[BM * LDK];
    __shared__ ushort Bs[BN * LDK];
    const int tid  = threadIdx.x;
    const int lane = tid & 63;
    const int wave = tid >> 6;
    const int wm = wave >> 1, wn = wave & 1;
    const int m0 = blockIdx.x * BM;
    const int n0 = blockIdx.y * BN;
    f32x4 acc[4][4] = {};
    const int a_row = tid >> 3;
    const int a_kc  = (tid & 7) * 4;
    const int b_k  = tid >> 5;
    const int b_nc = (tid & 31) * 4;
    const int fr = lane & 15;
    const int fg = lane >> 4;
    for (int kt = 0; kt < H2_; kt += 32) {
        #pragma unroll
        for (int p = 0; p < 4; ++p) {
            int row = a_row + p * 32;
            float4 v = *(const float4*)&A[(size_t)(m0 + row) * H2_ + kt + a_kc];
            ushort4 h;
            h.x = f2bf(v.x); h.y = f2bf(v.y); h.z = f2bf(v.z); h.w = f2bf(v.w);
            *(ushort4*)&As[row * LDK + a_kc] = h;
        }
        #pragma unroll
        for (int p = 0; p < 4; ++p) {
            int k = b_k + p * 8;
            float4 v = *(const float4*)&Bmat[(size_t)(kt + k) * H2_ + n0 + b_nc];
            Bs[(b_nc + 0) * LDK + k] = f2bf(v.x);
            Bs[(b_nc + 1) * LDK + k] = f2bf(v.y);
            Bs[(b_nc + 2) * LDK + k] = f2bf(v.z);
            Bs[(b_nc + 3) * LDK + k] = f2bf(v.w);
        }
        __syncthreads();
        bf16x8 af[4], bfr[4];
        #pragma unroll
        for (int i = 0; i < 4; ++i)
            af[i] = *(const bf16x8*)&As[(wm * 64 + i * 16 + fr) * LDK + fg * 8];
        #pragma unroll
        for (int j = 0; j < 4; ++j)
            bfr[j] = *(const bf16x8*)&Bs[(wn * 64 + j * 16 + fr) * LDK + fg * 8];
        #pragma unroll
        for (int i = 0; i < 4; ++i)
            #pragma unroll
            for (int j = 0; j < 4; ++j)
                acc[i][j] = __builtin_amdgcn_mfma_f32_16x16x32_bf16(af[i], bfr[j], acc[i][j], 0, 0, 0);
        __syncthreads();
    }
    const int b = m0 >> 9;
    float dec4[4], wc4[4], vq4[4];
    #pragma unroll
    for (int j = 0; j < 4; ++j) {
        int n = n0 + wn * 64 + j * 16 + fr;
        dec4[j] = dec[b * H2_ + n];
        wc4[j]  = Wc[n];
        vq4[j]  = vq[n];
    }
    #pragma unroll
    for (int i = 0; i < 4; ++i) {
        #pragma unroll
        for (int r = 0; r < 4; ++r) {
            int ml = wm * 64 + i * 16 + fg * 4 + r;
            int m  = m0 + ml;
            float cv = cov[b * L_ + (m & (L_ - 1))];
            float s = 0.f;
            #pragma unroll
            for (int j = 0; j < 4; ++j) {
                float att = acc[i][j][r] + dec4[j] + cv * wc4[j];
                s += fast_tanh(att) * vq4[j];
            }
            s += __shfl_xor(s, 1);
            s += __shfl_xor(s, 2);
            s += __shfl_xor(s, 4);
            s += __shfl_xor(s, 8);
            if (fr == 0)
                scores_part[(size_t)(blockIdx.y * 2 + wn) * M_ + m] = s;
        }
    }
}

// -------------------------------------------------------------------------
// FUSED softmax + cqt: grid (4 k-blocks, 64 b), 256 threads.
// -------------------------------------------------------------------------
__global__ __launch_bounds__(256) void softcqt_kernel(
    const float* __restrict__ scores_part, // (16, M)
    const float* __restrict__ mask,
    const float* __restrict__ cov,
    const ushort* __restrict__ Abf,        // (M, 1024) bf16
    float* __restrict__ out_alpha,
    float* __restrict__ out_newcov,
    float* __restrict__ c_q_t)
{
    const int b  = blockIdx.y;
    const int kb = blockIdx.x;       // 0..3
    const int t  = threadIdx.x;      // 0..255
    const int m0 = b * L_ + t;
    const int m1 = m0 + 256;

    float s0 = 0.f, s1 = 0.f;
    #pragma unroll
    for (int p = 0; p < 16; ++p) {
        s0 += scores_part[(size_t)p * M_ + m0];
        s1 += scores_part[(size_t)p * M_ + m1];
    }

    __shared__ float red[4];
    __shared__ float al[L_];

    float mx = fmaxf(s0, s1);
    #pragma unroll
    for (int o = 1; o < 64; o <<= 1) mx = fmaxf(mx, __shfl_xor(mx, o));
    if ((t & 63) == 0) red[t >> 6] = mx;
    __syncthreads();
    mx = fmaxf(fmaxf(red[0], red[1]), fmaxf(red[2], red[3]));
    __syncthreads();                  // red reuse guard

    float e0 = expf(s0 - mx) * mask[m0];
    float e1 = expf(s1 - mx) * mask[m1];
    float sm = e0 + e1;
    #pragma unroll
    for (int o = 1; o < 64; o <<= 1) sm += __shfl_xor(sm, o);
    if ((t & 63) == 0) red[t >> 6] = sm;
    __syncthreads();
    float tot = red[0] + red[1] + red[2] + red[3];

    float a0 = e0 / tot, a1 = e1 / tot;
    al[t]       = a0;
    al[t + 256] = a1;
    if (kb == 0) {
        out_alpha[m0]  = a0;
        out_alpha[m1]  = a1;
        out_newcov[m0] = cov[m0] + a0;
        out_newcov[m1] = cov[m1] + a1;
    }
    __syncthreads();

    const int k = kb * 256 + t;
    float acc = 0.f;
    const ushort* p = &Abf[(size_t)b * L_ * H2_ + k];
    #pragma unroll 8
    for (int l = 0; l < L_; ++l) {
        float v = __uint_as_float((uint)p[(size_t)l * H2_] << 16);
        acc += al[l] * v;
    }
    c_q_t[b * H2_ + k] = acc;
}

// -------------------------------------------------------------------------
// Fallback softmax / cqt (fp32) — only if ws too small.
// -------------------------------------------------------------------------
__global__ __launch_bounds__(512) void softmax_kernel(
    const float* __restrict__ scores_part,
    const float* __restrict__ mask,
    const float* __restrict__ cov,
    float* __restrict__ out_alpha,
    float* __restrict__ out_newcov)
{
    int b = blockIdx.x;
    int l = threadIdx.x;
    int m = b * L_ + l;
    float s = 0.f;
    #pragma unroll
    for (int p = 0; p < 16; ++p) s += scores_part[(size_t)p * M_ + m];
    __shared__ float red[8];
    float mx = s;
    #pragma unroll
    for (int o = 1; o < 64; o <<= 1) mx = fmaxf(mx, __shfl_xor(mx, o));
    int wid = l >> 6;
    if ((l & 63) == 0) red[wid] = mx;
    __syncthreads();
    mx = red[0];
    #pragma unroll
    for (int p = 1; p < 8; ++p) mx = fmaxf(mx, red[p]);
    __syncthreads();
    float e = expf(s - mx) * mask[m];
    float sm = e;
    #pragma unroll
    for (int o = 1; o < 64; o <<= 1) sm += __shfl_xor(sm, o);
    if ((l & 63) == 0) red[wid] = sm;
    __syncthreads();
    float tot = 0.f;
    #pragma unroll
    for (int p = 0; p < 8; ++p) tot += red[p];
    float alpha = e / tot;
    out_alpha[m]  = alpha;
    out_newcov[m] = cov[m] + alpha;
}

__global__ __launch_bounds__(256) void cqt_kernel(
    const float* __restrict__ alpha, const float* __restrict__ pai_q,
    float* __restrict__ out)
{
    int b = blockIdx.y;
    int k = blockIdx.x * 256 + threadIdx.x;
    __shared__ float al[L_];
    al[threadIdx.x]       = alpha[b * L_ + threadIdx.x];
    al[threadIdx.x + 256] = alpha[b * L_ + threadIdx.x + 256];
    __syncthreads();
    float acc = 0.f;
    const float* p = &pai_q[(size_t)b * L_ * H2_ + k];
    #pragma unroll 8
    for (int l = 0; l < L_; ++l) acc += al[l] * p[(size_t)l * H2_];
    out[b * H2_ + k] = acc;
}

extern "C" void kernel_launch(void* const* d_in, const int* in_sizes, int n_in,
                              void* d_out, int out_size, void* d_ws, size_t ws_size,
                              hipStream_t stream)
{
    const float* s_t_hat = (const float*)d_in[0];
    const float* pai_q   = (const float*)d_in[1];
    const float* mask    = (const float*)d_in[2];
    const float* cov     = (const float*)d_in[3];
    const float* W_q     = (const float*)d_in[4];
    const float* W_qs_w  = (const float*)d_in[5];
    const float* W_qs_b  = (const float*)d_in[6];
    const float* W_c     = (const float*)d_in[7];
    const float* v_q     = (const float*)d_in[8];

    float* out     = (float*)d_out;
    float* c_q_t   = out;
    float* alpha   = out + B_ * H2_;
    float* newcov  = alpha + B_ * L_;

    // ws: dec 262144 | scores_part 2097152 | Bbf 2097152 | Abf 67108864
    // dec_part (4 MB) time-aliases Abf (used before convertA writes it).
    char* ws = (char*)d_ws;
    float*  dec         = (float*)ws;
    float*  scores_part = (float*)(ws + 262144);
    ushort* Bbf         = (ushort*)(ws + 262144 + 2097152);
    ushort* Abf         = (ushort*)(ws + 262144 + 2097152 + 2097152);
    float*  dec_part    = (float*)Abf;
    const size_t ws_needed = 262144ull + 2097152ull + 2097152ull + 67108864ull;
    const size_t ws_min_fb = 262144ull + 2097152ull;

    if (ws_size >= ws_needed) {
        dec_split_kernel<<<dim3(16, KSPLIT), 256, 0, stream>>>(s_t_hat, W_qs_w, dec_part);
        decred_convB_kernel<<<dim3(1280), 256, 0, stream>>>(
            dec_part, W_qs_b, dec, W_q, Bbf);
        convertA_kernel<<<dim3((M_ * H2_) / (256 * 8)), 256, 0, stream>>>(pai_q, Abf);
        score_kernel3<<<dim3(M_ / BM, H2_ / BN), 256, 0, stream>>>(
            Abf, Bbf, dec, cov, W_c, v_q, scores_part);
        softcqt_kernel<<<dim3(4, B_), 256, 0, stream>>>(
            scores_part, mask, cov, Abf, alpha, newcov, c_q_t);
    } else if (ws_size >= ws_min_fb) {
        dec_kernel<<<dim3(4, 16), 256, 0, stream>>>(s_t_hat, W_qs_w, W_qs_b, dec);
        score_kernel_fb<<<dim3(M_ / BM, H2_ / BN), 256, 0, stream>>>(
            pai_q, W_q, dec, cov, W_c, v_q, scores_part);
        softmax_kernel<<<dim3(B_), 512, 0, stream>>>(scores_part, mask, cov, alpha, newcov);
        cqt_kernel<<<dim3(4, B_), 256, 0, stream>>>(alpha, pai_q, c_q_t);
    }
}